// Round 3
// baseline (187.855 us; speedup 1.0000x reference)
//
#include <hip/hip_runtime.h>

#define NB     64            // batch
#define HH     512
#define WW     512
#define HWSZ   (HH * WW)     // 262144 floats per batch image
#define NPTS   512
#define RBPB   4             // reduce blocks per batch
#define NRB    (NB * RBPB)   // 256 reduce-role blocks
#define NBLK   (NB + NRB)    // 320 total blocks
#define HSLOTS 8192          // LDS hash slots (64 KB total)
#define MAGIC  0x13579BDFu   // != 0xAAAAAAAA poison

__device__ __forceinline__ float waveReduceSum(float v) {
    for (int o = 32; o > 0; o >>= 1) v += __shfl_down(v, o);
    return v;
}

__device__ __forceinline__ void publish(unsigned* flag) {
    __threadfence();
    __hip_atomic_store(flag, MAGIC, __ATOMIC_RELEASE, __HIP_MEMORY_SCOPE_AGENT);
}

__device__ __forceinline__ float ld_agent(const float* p) {
    return __hip_atomic_load(p, __ATOMIC_RELAXED, __HIP_MEMORY_SCOPE_AGENT);
}

// Single fused kernel. Grid = 320 blocks x 512 threads.
//  blocks [0, NB)      : scatter role -> TS/T2/DOT per batch (LDS hash dedup)
//  blocks [NB, NBLK)   : reduce role  -> Spart/P2part per quarter-batch chunk
//  block 0 / thread 0  : spins on flags, then finalizes the 3 outputs in f64.
__global__ __launch_bounds__(512)
void k_all(const float* __restrict__ pred, const float* __restrict__ points,
           const int* __restrict__ pHin, const int* __restrict__ pWin,
           const int* __restrict__ pCell,
           float* __restrict__ Spart, float* __restrict__ P2part,
           float* __restrict__ T2, float* __restrict__ DOT, float* __restrict__ TS,
           unsigned* __restrict__ flags, float* __restrict__ out) {
    __shared__ unsigned keys[HSLOTS];
    __shared__ float    vals[HSLOTS];
    const int tid = threadIdx.x;

    if (blockIdx.x >= NB) {
        // ---------------- reduce role ----------------
        const int rb = blockIdx.x - NB;                       // 0..255
        const float4* base = (const float4*)pred + (size_t)rb * (HWSZ / RBPB / 4);
        float s = 0.f, q = 0.f;
#pragma unroll
        for (int i = 0; i < 32; ++i) {                        // 32*512 = 16384 float4
            float4 v = base[tid + i * 512];
            s += (v.x + v.y) + (v.z + v.w);
            q += v.x * v.x + v.y * v.y + v.z * v.z + v.w * v.w;
        }
        s = waveReduceSum(s);
        q = waveReduceSum(q);
        const int wave = tid >> 6, lane = tid & 63;
        if (lane == 0) { vals[wave] = s; vals[8 + wave] = q; }
        __syncthreads();
        if (tid == 0) {
            float a = 0.f, b2 = 0.f;
            for (int w = 0; w < 8; ++w) { a += vals[w]; b2 += vals[8 + w]; }
            Spart[rb] = a; P2part[rb] = b2;
            publish(&flags[NB + rb]);
        }
        return;
    }

    // ---------------- scatter role ----------------
    const int b = blockIdx.x;
    for (int i = tid; i < HSLOTS; i += 512) { keys[i] = 0xFFFFFFFFu; vals[i] = 0.f; }
    __syncthreads();

    const float scale_w = (float)WW / (float)(*pWin);
    const float scale_h = (float)HH / (float)(*pHin);
    const float wEdge = expf(-0.5f);
    const float wDiag = expf(-0.70710678118654752440f);       // exp(-sqrt(2)/2)

    float wsum = 0.f;
    {
        const float2 pt = ((const float2*)points)[(size_t)b * NPTS + tid];
        int x = (int)fminf(fmaxf(pt.x * scale_w, 0.f), (float)(WW - 1));
        int y = (int)fminf(fmaxf(pt.y * scale_h, 0.f), (float)(HH - 1));
#pragma unroll
        for (int dy = -1; dy <= 1; ++dy)
#pragma unroll
            for (int dx = -1; dx <= 1; ++dx) {
                int ny = y + dy, nx = x + dx;
                if (ny < 0 || ny >= HH || nx < 0 || nx >= WW) continue;
                int d2 = dy * dy + dx * dx;
                float w = (d2 == 0) ? 1.f : ((d2 == 1) ? wEdge : wDiag);
                wsum += w;
                unsigned key = (unsigned)(ny * WW + nx);
                unsigned h = (key * 2654435761u) >> 19;       // top 13 bits -> [0,8192)
                for (;;) {
                    unsigned old = atomicCAS(&keys[h], 0xFFFFFFFFu, key);
                    if (old == 0xFFFFFFFFu || old == key) { atomicAdd(&vals[h], w); break; }
                    h = (h + 1) & (HSLOTS - 1);
                }
            }
    }
    __syncthreads();

    float t2 = 0.f, dot = 0.f;
    const float* pb = pred + (size_t)b * HWSZ;
    for (int i = tid; i < HSLOTS; i += 512) {
        unsigned key = keys[i];
        if (key != 0xFFFFFFFFu) {
            float t = vals[i];
            t2  += t * t;
            dot += t * pb[key];
        }
    }

    wsum = waveReduceSum(wsum);
    t2   = waveReduceSum(t2);
    dot  = waveReduceSum(dot);
    __syncthreads();                 // done reading vals; reuse as scratch
    const int wave = tid >> 6, lane = tid & 63;
    if (lane == 0) { vals[wave] = wsum; vals[8 + wave] = t2; vals[16 + wave] = dot; }
    __syncthreads();
    if (tid == 0) {
        float a0 = 0.f, a1 = 0.f, a2 = 0.f;
        for (int w = 0; w < 8; ++w) { a0 += vals[w]; a1 += vals[8 + w]; a2 += vals[16 + w]; }
        TS[b] = a0; T2[b] = a1; DOT[b] = a2;
        publish(&flags[b]);
    }

    // ---------------- finalize (block 0, thread 0) ----------------
    if (b == 0 && tid == 0) {
        for (int i = 0; i < NBLK; ++i)
            while (__hip_atomic_load(&flags[i], __ATOMIC_ACQUIRE, __HIP_MEMORY_SCOPE_AGENT) != MAGIC)
                __builtin_amdgcn_s_sleep(2);

        const double cell = (double)(*pCell);
        double cl = 0.0, sl = 0.0;
        for (int t = 0; t < NB; ++t) {
            double s = 0.0, p2 = 0.0;
#pragma unroll
            for (int c = 0; c < RBPB; ++c) {
                s  += (double)ld_agent(&Spart[t * RBPB + c]);
                p2 += (double)ld_agent(&P2part[t * RBPB + c]);
            }
            cl += fabs(s / cell - (double)NPTS);
            double sn = s + 1e-8;
            double ts = (double)ld_agent(&TS[t]);
            double term = p2 / (sn * sn)
                        - 2.0 * (double)ld_agent(&DOT[t]) / (sn * ts)
                        + (double)ld_agent(&T2[t]) / (ts * ts);
            sl += term / (double)HWSZ;
        }
        double count_loss   = cl / (double)NB;
        double spatial_loss = sl / (double)NB;
        double total = 2.5 * count_loss + 0.1 * spatial_loss;   // scale_loss == 0
        out[0] = (float)total;
        out[1] = (float)count_loss;
        out[2] = (float)spatial_loss;
    }
}

extern "C" void kernel_launch(void* const* d_in, const int* in_sizes, int n_in,
                              void* d_out, int out_size, void* d_ws, size_t ws_size,
                              hipStream_t stream) {
    const float* pred   = (const float*)d_in[0];
    const float* points = (const float*)d_in[1];
    const int*   cell   = (const int*)d_in[2];
    const int*   hin    = (const int*)d_in[3];
    const int*   win    = (const int*)d_in[4];
    float* out = (float*)d_out;

    float*    Spart  = (float*)d_ws;         // NRB floats
    float*    P2part = Spart + NRB;          // NRB floats
    float*    T2     = Spart + 2 * NRB;      // NB floats
    float*    DOT    = T2 + NB;              // NB floats
    float*    TS     = DOT + NB;             // NB floats
    unsigned* flags  = (unsigned*)(TS + NB); // NBLK words (poisoned 0xAA... != MAGIC)

    k_all<<<NBLK, 512, 0, stream>>>(pred, points, hin, win, cell,
                                    Spart, P2part, T2, DOT, TS, flags, out);
}

// Round 4
// 122.123 us; speedup vs baseline: 1.5382x; 1.5382x over previous
//
#include <hip/hip_runtime.h>

#define NB     64            // batch
#define HH     512
#define WW     512
#define HWSZ   (HH * WW)     // 262144 floats per batch image
#define NPTS   512
#define RBPB   4             // reduce blocks per batch
#define NRB    (NB * RBPB)   // 256 reduce-role blocks
#define NBLK   (NB + NRB)    // 320 total blocks
#define HSLOTS 8192          // LDS hash slots (64 KB total)
#define MAGIC  0x13579BDFu   // != 0xAAAAAAAA poison

__device__ __forceinline__ float waveReduceSum(float v) {
    for (int o = 32; o > 0; o >>= 1) v += __shfl_down(v, o);
    return v;
}

__device__ __forceinline__ void publish(unsigned* flag) {
    __threadfence();
    __hip_atomic_store(flag, MAGIC, __ATOMIC_RELEASE, __HIP_MEMORY_SCOPE_AGENT);
}

__device__ __forceinline__ float ld_agent(const float* p) {
    return __hip_atomic_load(p, __ATOMIC_RELAXED, __HIP_MEMORY_SCOPE_AGENT);
}

// Single fused kernel. Grid = 320 blocks x 512 threads.
//  blocks [0, NB)      : scatter role -> TS/T2/DOT per batch (LDS hash dedup)
//  blocks [NB, NBLK)   : reduce role  -> Spart/P2part per quarter-batch chunk
//  block 0             : 320 threads poll one flag each (parallel, ~1 coherent
//                        load latency instead of 320 serial), then 64-lane
//                        f64 finalize.
__global__ __launch_bounds__(512)
void k_all(const float* __restrict__ pred, const float* __restrict__ points,
           const int* __restrict__ pHin, const int* __restrict__ pWin,
           const int* __restrict__ pCell,
           float* __restrict__ Spart, float* __restrict__ P2part,
           float* __restrict__ T2, float* __restrict__ DOT, float* __restrict__ TS,
           unsigned* __restrict__ flags, float* __restrict__ out) {
    __shared__ unsigned keys[HSLOTS];
    __shared__ float    vals[HSLOTS];
    const int tid = threadIdx.x;

    if (blockIdx.x >= NB) {
        // ---------------- reduce role ----------------
        const int rb = blockIdx.x - NB;                       // 0..255
        const float4* base = (const float4*)pred + (size_t)rb * (HWSZ / RBPB / 4);
        float s = 0.f, q = 0.f;
#pragma unroll
        for (int i = 0; i < 32; ++i) {                        // 32*512 = 16384 float4
            float4 v = base[tid + i * 512];
            s += (v.x + v.y) + (v.z + v.w);
            q += v.x * v.x + v.y * v.y + v.z * v.z + v.w * v.w;
        }
        s = waveReduceSum(s);
        q = waveReduceSum(q);
        const int wave = tid >> 6, lane = tid & 63;
        if (lane == 0) { vals[wave] = s; vals[8 + wave] = q; }
        __syncthreads();
        if (tid == 0) {
            float a = 0.f, b2 = 0.f;
            for (int w = 0; w < 8; ++w) { a += vals[w]; b2 += vals[8 + w]; }
            Spart[rb] = a; P2part[rb] = b2;
            publish(&flags[NB + rb]);
        }
        return;
    }

    // ---------------- scatter role ----------------
    const int b = blockIdx.x;
    for (int i = tid; i < HSLOTS; i += 512) { keys[i] = 0xFFFFFFFFu; vals[i] = 0.f; }
    __syncthreads();

    const float scale_w = (float)WW / (float)(*pWin);
    const float scale_h = (float)HH / (float)(*pHin);
    const float wEdge = expf(-0.5f);
    const float wDiag = expf(-0.70710678118654752440f);       // exp(-sqrt(2)/2)

    float wsum = 0.f;
    {
        const float2 pt = ((const float2*)points)[(size_t)b * NPTS + tid];
        int x = (int)fminf(fmaxf(pt.x * scale_w, 0.f), (float)(WW - 1));
        int y = (int)fminf(fmaxf(pt.y * scale_h, 0.f), (float)(HH - 1));
#pragma unroll
        for (int dy = -1; dy <= 1; ++dy)
#pragma unroll
            for (int dx = -1; dx <= 1; ++dx) {
                int ny = y + dy, nx = x + dx;
                if (ny < 0 || ny >= HH || nx < 0 || nx >= WW) continue;
                int d2 = dy * dy + dx * dx;
                float w = (d2 == 0) ? 1.f : ((d2 == 1) ? wEdge : wDiag);
                wsum += w;
                unsigned key = (unsigned)(ny * WW + nx);
                unsigned h = (key * 2654435761u) >> 19;       // top 13 bits -> [0,8192)
                for (;;) {
                    unsigned old = atomicCAS(&keys[h], 0xFFFFFFFFu, key);
                    if (old == 0xFFFFFFFFu || old == key) { atomicAdd(&vals[h], w); break; }
                    h = (h + 1) & (HSLOTS - 1);
                }
            }
    }
    __syncthreads();

    float t2 = 0.f, dot = 0.f;
    const float* pb = pred + (size_t)b * HWSZ;
    for (int i = tid; i < HSLOTS; i += 512) {
        unsigned key = keys[i];
        if (key != 0xFFFFFFFFu) {
            float t = vals[i];
            t2  += t * t;
            dot += t * pb[key];
        }
    }

    wsum = waveReduceSum(wsum);
    t2   = waveReduceSum(t2);
    dot  = waveReduceSum(dot);
    __syncthreads();                 // done reading vals; reuse as scratch
    const int wave = tid >> 6, lane = tid & 63;
    if (lane == 0) { vals[wave] = wsum; vals[8 + wave] = t2; vals[16 + wave] = dot; }
    __syncthreads();
    if (tid == 0) {
        float a0 = 0.f, a1 = 0.f, a2 = 0.f;
        for (int w = 0; w < 8; ++w) { a0 += vals[w]; a1 += vals[8 + w]; a2 += vals[16 + w]; }
        TS[b] = a0; T2[b] = a1; DOT[b] = a2;
        publish(&flags[b]);
    }

    // ---------------- finalize (block 0, all threads) ----------------
    if (b == 0) {
        // Parallel wait: thread i owns flags[i]. Each poll is one coherent
        // load; all 320 proceed concurrently (R3's serial scan cost ~100 us).
        if (tid < NBLK) {
            while (__hip_atomic_load(&flags[tid], __ATOMIC_ACQUIRE, __HIP_MEMORY_SCOPE_AGENT) != MAGIC)
                __builtin_amdgcn_s_sleep(8);
        }
        __syncthreads();   // all flags observed; producers' data visible via L2-bypass loads

        double cl = 0.0, sl = 0.0;
        if (tid < NB) {
            double s = 0.0, p2 = 0.0;
#pragma unroll
            for (int c = 0; c < RBPB; ++c) {
                s  += (double)ld_agent(&Spart[tid * RBPB + c]);
                p2 += (double)ld_agent(&P2part[tid * RBPB + c]);
            }
            cl = fabs(s / (double)(*pCell) - (double)NPTS);
            double sn = s + 1e-8;
            double ts = (double)ld_agent(&TS[tid]);
            double term = p2 / (sn * sn)
                        - 2.0 * (double)ld_agent(&DOT[tid]) / (sn * ts)
                        + (double)ld_agent(&T2[tid]) / (ts * ts);
            sl = term / (double)HWSZ;
        }
        if (tid < 64) {    // wave 0 only: 64-lane f64 shuffle reduce
            for (int o = 32; o > 0; o >>= 1) {
                cl += __shfl_down(cl, o);
                sl += __shfl_down(sl, o);
            }
            if (tid == 0) {
                double count_loss   = cl / (double)NB;
                double spatial_loss = sl / (double)NB;
                double total = 2.5 * count_loss + 0.1 * spatial_loss;   // scale_loss == 0
                out[0] = (float)total;
                out[1] = (float)count_loss;
                out[2] = (float)spatial_loss;
            }
        }
    }
}

extern "C" void kernel_launch(void* const* d_in, const int* in_sizes, int n_in,
                              void* d_out, int out_size, void* d_ws, size_t ws_size,
                              hipStream_t stream) {
    const float* pred   = (const float*)d_in[0];
    const float* points = (const float*)d_in[1];
    const int*   cell   = (const int*)d_in[2];
    const int*   hin    = (const int*)d_in[3];
    const int*   win    = (const int*)d_in[4];
    float* out = (float*)d_out;

    float*    Spart  = (float*)d_ws;         // NRB floats
    float*    P2part = Spart + NRB;          // NRB floats
    float*    T2     = Spart + 2 * NRB;      // NB floats
    float*    DOT    = T2 + NB;              // NB floats
    float*    TS     = DOT + NB;             // NB floats
    unsigned* flags  = (unsigned*)(TS + NB); // NBLK words (poisoned 0xAA... != MAGIC)

    k_all<<<NBLK, 512, 0, stream>>>(pred, points, hin, win, cell,
                                    Spart, P2part, T2, DOT, TS, flags, out);
}